// Round 1
// baseline (1083.810 us; speedup 1.0000x reference)
//
#include <hip/hip_runtime.h>
#include <stdint.h>

// PrecondTiming round 8. Pipeline:
//   K1: multisplit flat pins into NB1=160 pin-range bins -> items (pin,w)
//       (unchanged from round 7, ~155us)
//   K2: per pin-bin gather node=pin2node[pin] (512KB slice L2-resident via
//       bin-major XCD-affine mapping, VERIFIED r6), then DIRECT atomicAdd
//       into a per-XCD-replicated accumulator part[xcd][node] (8 x 4MB).
//       Replaces r7's node-multisplit (165us, barrier/latency-bound:
//       VALU 8%, HBM 22%) -- no LDS, no barriers, no items2 round-trip.
//   K3: out[n] = beta * sum_x part[x][n]  (36MB streamed, ~10us).
//       Replaces r7's LDS-accumulate K3 (~150us re-reading 134MB items2).
//
// Rationale: all three r7 kernels sat at ~150-165us each, none BW- or
// ALU-bound; the 256-way node multisplit existed only to make K3's
// accumulation LDS-local. Per-XCD replication (blockIdx&7 -> XCD, r6
// verified) keeps each 4MB copy XCD-private: 8x less same-address
// contention, and no-return global_atomic_add_f32 is fire-and-forget.
// Correctness does not depend on the XCD mapping (atomics are
// device-scope); only locality does.

#define TILE 4096
#define THREADS 512
#define IPT  8                  // items per thread (TILE / THREADS)
#define NB1  160
#define SHIFT1 17               // pin >> 17 : 160 bins cover 20,971,520 pins
#define CAP1 114688             // per-bin cap (expected 104,858; ~30-sigma)
#define TILES_PER_BIN1 28       // CAP1 / TILE
#define NXCD 8
#define CTRL_BYTES 8192         // zeroed: cur1 @0 (160 ints)

typedef unsigned long long item_t;   // low32 = key (pin), high32 = w bits
typedef int   int4_ev   __attribute__((ext_vector_type(4)));
typedef float float4_ev __attribute__((ext_vector_type(4)));
typedef unsigned long long ull2_ev __attribute__((ext_vector_type(2)));

__device__ __forceinline__ item_t pack_item(uint32_t key, float w) {
    return (item_t)key | ((item_t)__float_as_uint(w) << 32);
}

// ---- block-level tile multisplit (512 thr): counting-sort a tile in LDS,
// ---- write each bin's run contiguously to its global bin region.
// ---- Bins derived from key via >> shift (max 256 bins). 5 barriers total.
__device__ __forceinline__ void multisplit_flush(
    uint32_t (&key)[IPT], float (&wv)[IPT], int (&bin)[IPT],  // bin<0 = invalid
    int tile_cnt, int shift,
    int* __restrict__ gcur, item_t* __restrict__ gout, size_t cap)
{
    __shared__ int hist[256];
    __shared__ int basex[256];
    __shared__ int gbase[256];
    __shared__ int wsum[4];
    __shared__ item_t stage[TILE];
    const int t = threadIdx.x;

    if (t < 256) hist[t] = 0;
    __syncthreads();                                          // B1

    // pass A: per-bin rank via LDS atomics
    int rank[IPT];
#pragma unroll
    for (int k = 0; k < IPT; ++k)
        rank[k] = (bin[k] >= 0) ? atomicAdd(&hist[bin[k]], 1) : 0;
    __syncthreads();                                          // B2

    // pass B: wave-shuffle inclusive scan over 256 counters (waves 0-3)
    int val = (t < 256) ? hist[t] : 0;
    int inc = val;
#pragma unroll
    for (int d = 1; d < 64; d <<= 1) {
        int n = __shfl_up(inc, d, 64);
        if ((t & 63) >= d) inc += n;
    }
    if (t < 256 && (t & 63) == 63) wsum[t >> 6] = inc;
    __syncthreads();                                          // B3
    if (t < 256) {
        int w = t >> 6, prefix = 0;
        if (w > 0) prefix += wsum[0];
        if (w > 1) prefix += wsum[1];
        if (w > 2) prefix += wsum[2];
        basex[t] = prefix + inc - val;                        // exclusive base
        gbase[t] = (val > 0) ? atomicAdd(&gcur[t], val) : 0;  // reserve range
    }
    __syncthreads();                                          // B4

    // pass D: scatter into LDS in bin-sorted order
#pragma unroll
    for (int k = 0; k < IPT; ++k) {
        if (bin[k] >= 0)
            stage[basex[bin[k]] + rank[k]] = pack_item(key[k], wv[k]);
    }
    __syncthreads();                                          // B5

    // pass E: coalesced write-out; bin recomputed from stored key
    for (int j = t; j < tile_cnt; j += THREADS) {
        item_t e = stage[j];
        int b = (int)((uint32_t)(e & 0xffffffffull) >> shift);
        long long dst = (long long)gbase[b] + (j - basex[b]);
        if (dst >= 0 && dst < (long long)cap)
            __builtin_nontemporal_store(e, &gout[(size_t)b * cap + (size_t)dst]);
    }
}

// ---- K1: stream flat pins + weights (vectorized), partition by pin range ----
__global__ __launch_bounds__(THREADS, 8) void k1_partition_pins(
    const int* __restrict__ flat_pins, const float* __restrict__ weights,
    int* __restrict__ cur1, item_t* __restrict__ items1, int total)
{
    const int tileBase = blockIdx.x * TILE;
    const int t = threadIdx.x;
    const int base = tileBase + t * IPT;        // 8 consecutive items/thread
    uint32_t key[IPT]; float wv[IPT]; int bin[IPT];

    if (base + IPT <= total) {
        int4_ev   p[2];
        float4_ev w;
#pragma unroll
        for (int v = 0; v < 2; ++v)
            p[v] = __builtin_nontemporal_load((const int4_ev*)(flat_pins + base) + v);
        w = __builtin_nontemporal_load((const float4_ev*)(weights + (base >> 1)));
#pragma unroll
        for (int k = 0; k < IPT; ++k) {
            int pin = p[k >> 2][k & 3];
            key[k] = (uint32_t)pin;
            wv[k]  = w[(k >> 1) & 3];           // arc = (base+k)>>1: 4 consecutive
            bin[k] = pin >> SHIFT1;
        }
    } else {
#pragma unroll
        for (int k = 0; k < IPT; ++k) {
            int i = base + k;
            bool ok = i < total;
            int pin = ok ? flat_pins[i] : 0;
            key[k] = (uint32_t)pin;
            wv[k]  = ok ? weights[i >> 1] : 0.f;
            bin[k] = ok ? (pin >> SHIFT1) : -1;
        }
    }
    int cnt = min(TILE, total - tileBase);
    multisplit_flush(key, wv, bin, cnt, SHIFT1, cur1, items1, (size_t)CAP1);
}

// ---- K2: per pin-bin gather (L2-resident 512KB slice), atomic accumulate
// ---- into this XCD's private 4MB copy. No LDS, no barriers.
__global__ __launch_bounds__(THREADS, 8) void k2_gather_atomic(
    const item_t* __restrict__ items1, const int* __restrict__ cur1,
    const int* __restrict__ pin2node,
    float* __restrict__ part, int num_nodes)
{
    // bin-major within each XCD residue (VERIFIED r6: keeps slices L2-resident)
    const int q = blockIdx.x;
    const int r = q & 7;                         // XCD residue -> private copy
    const int s = q >> 3;
    const int bin  = r + 8 * (s / TILES_PER_BIN1);
    const int tile = s % TILES_PER_BIN1;
    const int cnt = min(cur1[bin], (int)CAP1);
    const int tbase = tile * TILE;
    if (tbase >= cnt) return;

    float* __restrict__ dst = part + (size_t)r * (size_t)num_nodes;
    const item_t* src = items1 + (size_t)bin * CAP1;
    const int t = threadIdx.x;
    const int base = tbase + t * IPT;

    if (base + IPT <= cnt) {
        ull2_ev it[4];
#pragma unroll
        for (int v = 0; v < 4; ++v)
            it[v] = __builtin_nontemporal_load((const ull2_ev*)(src + base) + v);
#pragma unroll
        for (int k = 0; k < IPT; ++k) {
            item_t e = it[k >> 1][k & 1];
            int node = pin2node[(uint32_t)(e & 0xffffffffull)];  // L2-resident slice
            atomicAdd(&dst[node], __uint_as_float((uint32_t)(e >> 32)));
        }
    } else {
#pragma unroll
        for (int k = 0; k < IPT; ++k) {
            int i = base + k;
            if (i < cnt) {
                item_t e = src[i];
                int node = pin2node[(uint32_t)(e & 0xffffffffull)];
                atomicAdd(&dst[node], __uint_as_float((uint32_t)(e >> 32)));
            }
        }
    }
}

// ---- K3: out[n] = beta * sum over 8 XCD copies (36MB streamed) ----
__global__ __launch_bounds__(256) void k3_reduce(
    const float* __restrict__ part, const float* __restrict__ beta,
    float* __restrict__ out, int num_nodes)
{
    const float bt = beta[0];
    const int i4 = blockIdx.x * 256 + threadIdx.x;
    const int n = i4 * 4;
    if (n + 3 < num_nodes) {
        float4_ev s = {0.f, 0.f, 0.f, 0.f};
#pragma unroll
        for (int x = 0; x < NXCD; ++x)
            s += *(const float4_ev*)(part + (size_t)x * (size_t)num_nodes + n);
        *(float4_ev*)(out + n) = s * bt;
    } else {
        for (int k = 0; k < 4; ++k) {
            int nn = n + k;
            if (nn < num_nodes) {
                float s = 0.f;
#pragma unroll
                for (int x = 0; x < NXCD; ++x)
                    s += part[(size_t)x * (size_t)num_nodes + nn];
                out[nn] = s * bt;
            }
        }
    }
}

// ---- fallback (round-1, known-good ~830us): device-scope atomics ----
__global__ __launch_bounds__(256) void scatter_device(
    const float* __restrict__ beta, const float* __restrict__ tnet_weights,
    const long long* __restrict__ pin_pairs, const int* __restrict__ pin2node_map,
    float* __restrict__ out, int num_tnets)
{
    int t = blockIdx.x * blockDim.x + threadIdx.x;
    if (t >= num_tnets) return;
    long long pp = pin_pairs[t];
    float w = tnet_weights[t] * beta[0];
    atomicAdd(&out[pin2node_map[(int)(pp & 0xffffffffLL)]], w);
    atomicAdd(&out[pin2node_map[(int)(pp >> 32)]], w);
}

extern "C" void kernel_launch(void* const* d_in, const int* in_sizes, int n_in,
                              void* d_out, int out_size, void* d_ws, size_t ws_size,
                              hipStream_t stream) {
    const float* beta         = (const float*)d_in[0];
    const float* weights      = (const float*)d_in[1];
    const int*   flat_pins    = (const int*)d_in[2];
    const int*   pin2node     = (const int*)d_in[3];
    float* out = (float*)d_out;

    const int num_tnets = in_sizes[1];
    const int total     = in_sizes[2];       // 2 * num_tnets flat pin slots
    const int num_nodes = out_size;

    const size_t items1Bytes = (size_t)NB1 * CAP1 * sizeof(item_t);          // 146.8 MB
    const size_t partBytes   = (size_t)NXCD * (size_t)num_nodes * sizeof(float); // 32 MB

    int* cur1 = (int*)d_ws;                          // bytes [0, 640)
    const int gridTiles = (total + TILE - 1) / TILE;

    if (ws_size >= CTRL_BYTES + items1Bytes + partBytes) {
        item_t* items1 = (item_t*)((char*)d_ws + CTRL_BYTES);
        float*  part   = (float*)((char*)d_ws + CTRL_BYTES + items1Bytes);
        (void)hipMemsetAsync(d_ws, 0, CTRL_BYTES, stream);
        (void)hipMemsetAsync(part, 0, partBytes, stream);
        k1_partition_pins<<<gridTiles, THREADS, 0, stream>>>(
            flat_pins, weights, cur1, items1, total);
        k2_gather_atomic<<<NB1 * TILES_PER_BIN1, THREADS, 0, stream>>>(
            items1, cur1, pin2node, part, num_nodes);
        const int i4slots = (num_nodes + 3) / 4;
        k3_reduce<<<(i4slots + 255) / 256, 256, 0, stream>>>(
            part, beta, out, num_nodes);
    } else {
        (void)hipMemsetAsync(d_out, 0, (size_t)out_size * sizeof(float), stream);
        scatter_device<<<(num_tnets + 255) / 256, 256, 0, stream>>>(
            beta, weights, (const long long*)flat_pins, pin2node, out, num_tnets);
    }
}

// Round 2
// 590.307 us; speedup vs baseline: 1.8360x; 1.8360x over previous
//
#include <hip/hip_runtime.h>
#include <stdint.h>

// PrecondTiming round 9. Two-pass pipeline:
//   K1: stream flat pins + weights, gather node=pin2node[pin] DIRECTLY
//       (pin2node is 84MB -> fully L3-resident; gather line traffic
//       16.8M x 64B = 1.07GB from Infinity Cache, hidden under multisplit
//       machinery), multisplit by node into NB2=256 node bins.
//       Deletes r7's items1 268MB round-trip + one kernel's latency cost.
//   K2: per node-bin LDS accumulate, VECTORIZED 32B/thread/iter loads.
//       r7's K3 was latency-bound (1 block/CU, scalar 8B loads -> ~8KB/CU
//       in flight vs ~9.2KB needed at HBM latency; 150us for a 21us BW
//       floor). 2x ull2 loads/iter -> ~32KB/CU in flight -> BW-bound.
//
// Round-8 lesson (twice-confirmed): bulk global f32 atomics ~20G/s on
// this chip (826us for 16.8M, WRITE 524MB = accumulator thrashed out of
// L2) -- multisplit is mandatory; never atomic the bulk stream.

#define TILE 4096
#define THREADS 512
#define IPT  8                  // items per thread (TILE / THREADS)
#define NB2  256
#define SHIFT2 12               // node >> 12 : 256 bins cover 2^20 nodes
#define CAP2 81920              // per-bin cap (expected 65,536; ~64-sigma)
#define ACC_NODES 4096
#define CTRL_BYTES 8192         // zeroed: cur2 @0 (256 ints)

typedef unsigned long long item_t;   // low32 = key (node), high32 = w bits
typedef int   int4_ev   __attribute__((ext_vector_type(4)));
typedef float float4_ev __attribute__((ext_vector_type(4)));
typedef unsigned long long ull2_ev __attribute__((ext_vector_type(2)));

__device__ __forceinline__ item_t pack_item(uint32_t key, float w) {
    return (item_t)key | ((item_t)__float_as_uint(w) << 32);
}

// ---- block-level tile multisplit (512 thr): counting-sort a tile in LDS,
// ---- write each bin's run contiguously to its global bin region.
// ---- Bins derived from key via >> shift (max 256 bins). 5 barriers total.
__device__ __forceinline__ void multisplit_flush(
    uint32_t (&key)[IPT], float (&wv)[IPT], int (&bin)[IPT],  // bin<0 = invalid
    int tile_cnt, int shift,
    int* __restrict__ gcur, item_t* __restrict__ gout, size_t cap)
{
    __shared__ int hist[256];
    __shared__ int basex[256];
    __shared__ int gbase[256];
    __shared__ int wsum[4];
    __shared__ item_t stage[TILE];
    const int t = threadIdx.x;

    if (t < 256) hist[t] = 0;
    __syncthreads();                                          // B1

    // pass A: per-bin rank via LDS atomics
    int rank[IPT];
#pragma unroll
    for (int k = 0; k < IPT; ++k)
        rank[k] = (bin[k] >= 0) ? atomicAdd(&hist[bin[k]], 1) : 0;
    __syncthreads();                                          // B2

    // pass B: wave-shuffle inclusive scan over 256 counters (waves 0-3)
    int val = (t < 256) ? hist[t] : 0;
    int inc = val;
#pragma unroll
    for (int d = 1; d < 64; d <<= 1) {
        int n = __shfl_up(inc, d, 64);
        if ((t & 63) >= d) inc += n;
    }
    if (t < 256 && (t & 63) == 63) wsum[t >> 6] = inc;
    __syncthreads();                                          // B3
    if (t < 256) {
        int w = t >> 6, prefix = 0;
        if (w > 0) prefix += wsum[0];
        if (w > 1) prefix += wsum[1];
        if (w > 2) prefix += wsum[2];
        basex[t] = prefix + inc - val;                        // exclusive base
        gbase[t] = (val > 0) ? atomicAdd(&gcur[t], val) : 0;  // reserve range
    }
    __syncthreads();                                          // B4

    // pass D: scatter into LDS in bin-sorted order
#pragma unroll
    for (int k = 0; k < IPT; ++k) {
        if (bin[k] >= 0)
            stage[basex[bin[k]] + rank[k]] = pack_item(key[k], wv[k]);
    }
    __syncthreads();                                          // B5

    // pass E: coalesced write-out; bin recomputed from stored key
    for (int j = t; j < tile_cnt; j += THREADS) {
        item_t e = stage[j];
        int b = (int)((uint32_t)(e & 0xffffffffull) >> shift);
        long long dst = (long long)gbase[b] + (j - basex[b]);
        if (dst >= 0 && dst < (long long)cap)
            __builtin_nontemporal_store(e, &gout[(size_t)b * cap + (size_t)dst]);
    }
}

// ---- K1: stream pins+weights, gather node via L3-resident pin2node,
// ---- multisplit by node into 256 bins. One pass over the bulk data.
__global__ __launch_bounds__(THREADS, 8) void k1_gather_split(
    const int* __restrict__ flat_pins, const float* __restrict__ weights,
    const int* __restrict__ pin2node,
    int* __restrict__ cur2, item_t* __restrict__ items2, int total)
{
    const int tileBase = blockIdx.x * TILE;
    const int t = threadIdx.x;
    const int base = tileBase + t * IPT;        // 8 consecutive items/thread
    uint32_t key[IPT]; float wv[IPT]; int bin[IPT];

    if (base + IPT <= total) {
        int4_ev   p[2];
        float4_ev w;
#pragma unroll
        for (int v = 0; v < 2; ++v)
            p[v] = __builtin_nontemporal_load((const int4_ev*)(flat_pins + base) + v);
        w = __builtin_nontemporal_load((const float4_ev*)(weights + (base >> 1)));
        // issue all 8 gathers back-to-back (ILP=8) before any use
        int node[IPT];
#pragma unroll
        for (int k = 0; k < IPT; ++k)
            node[k] = pin2node[(uint32_t)p[k >> 2][k & 3]];
#pragma unroll
        for (int k = 0; k < IPT; ++k) {
            key[k] = (uint32_t)node[k];
            wv[k]  = w[(k >> 1) & 3];           // arc = (base+k)>>1: 4 consecutive
            bin[k] = node[k] >> SHIFT2;
        }
    } else {
#pragma unroll
        for (int k = 0; k < IPT; ++k) {
            int i = base + k;
            bool ok = i < total;
            int node = ok ? pin2node[(uint32_t)flat_pins[i]] : 0;
            key[k] = (uint32_t)node;
            wv[k]  = ok ? weights[i >> 1] : 0.f;
            bin[k] = ok ? (node >> SHIFT2) : -1;
        }
    }
    int cnt = min(TILE, total - tileBase);
    multisplit_flush(key, wv, bin, cnt, SHIFT2, cur2, items2, (size_t)CAP2);
}

// ---- K2: LDS accumulate per node-bin (1024 thr), vectorized 32B loads ----
__global__ __launch_bounds__(1024) void k2_accumulate(
    const item_t* __restrict__ items2, const int* __restrict__ cur2,
    const float* __restrict__ beta, float* __restrict__ out, int num_nodes)
{
    __shared__ float acc[ACC_NODES];
    const int b = blockIdx.x;
    const int t = threadIdx.x;
    for (int i = t; i < ACC_NODES; i += 1024) acc[i] = 0.f;
    __syncthreads();
    const int cnt = min(cur2[b], (int)CAP2);
    const item_t* src = items2 + (size_t)b * CAP2;

    // vector body: 4 items (32B) per thread per iter -> 2x ull2 loads
    const int nvec = cnt >> 2;
    for (int g = t; g < nvec; g += 1024) {
        const item_t* p = src + ((size_t)g << 2);
        ull2_ev a0 = __builtin_nontemporal_load((const ull2_ev*)p);
        ull2_ev a1 = __builtin_nontemporal_load((const ull2_ev*)p + 1);
#pragma unroll
        for (int k = 0; k < 2; ++k) {
            item_t e0 = a0[k], e1 = a1[k];
            atomicAdd(&acc[(uint32_t)(e0 & 0xffffffffull) & (ACC_NODES - 1)],
                      __uint_as_float((uint32_t)(e0 >> 32)));
            atomicAdd(&acc[(uint32_t)(e1 & 0xffffffffull) & (ACC_NODES - 1)],
                      __uint_as_float((uint32_t)(e1 >> 32)));
        }
    }
    // tail
    for (int i = (nvec << 2) + t; i < cnt; i += 1024) {
        item_t e = __builtin_nontemporal_load(&src[i]);
        atomicAdd(&acc[(uint32_t)(e & 0xffffffffull) & (ACC_NODES - 1)],
                  __uint_as_float((uint32_t)(e >> 32)));
    }
    __syncthreads();
    const float bt = beta[0];
    const int nodeBase = b << SHIFT2;
    for (int i = t; i < ACC_NODES; i += 1024) {
        int n = nodeBase + i;
        if (n < num_nodes) out[n] = acc[i] * bt;
    }
}

// ---- fallback (round-1, known-good ~830us): device-scope atomics ----
__global__ __launch_bounds__(256) void scatter_device(
    const float* __restrict__ beta, const float* __restrict__ tnet_weights,
    const long long* __restrict__ pin_pairs, const int* __restrict__ pin2node_map,
    float* __restrict__ out, int num_tnets)
{
    int t = blockIdx.x * blockDim.x + threadIdx.x;
    if (t >= num_tnets) return;
    long long pp = pin_pairs[t];
    float w = tnet_weights[t] * beta[0];
    atomicAdd(&out[pin2node_map[(int)(pp & 0xffffffffLL)]], w);
    atomicAdd(&out[pin2node_map[(int)(pp >> 32)]], w);
}

extern "C" void kernel_launch(void* const* d_in, const int* in_sizes, int n_in,
                              void* d_out, int out_size, void* d_ws, size_t ws_size,
                              hipStream_t stream) {
    const float* beta         = (const float*)d_in[0];
    const float* weights      = (const float*)d_in[1];
    const int*   flat_pins    = (const int*)d_in[2];
    const int*   pin2node     = (const int*)d_in[3];
    float* out = (float*)d_out;

    const int num_tnets = in_sizes[1];
    const int total     = in_sizes[2];       // 2 * num_tnets flat pin slots
    const int num_nodes = out_size;

    const size_t items2Bytes = (size_t)NB2 * CAP2 * sizeof(item_t);  // 167.8 MB

    int* cur2 = (int*)d_ws;                          // bytes [0, 1024)
    const int gridTiles = (total + TILE - 1) / TILE;

    if (ws_size >= CTRL_BYTES + items2Bytes) {
        item_t* items2 = (item_t*)((char*)d_ws + CTRL_BYTES);
        (void)hipMemsetAsync(d_ws, 0, CTRL_BYTES, stream);
        k1_gather_split<<<gridTiles, THREADS, 0, stream>>>(
            flat_pins, weights, pin2node, cur2, items2, total);
        k2_accumulate<<<NB2, 1024, 0, stream>>>(items2, cur2, beta, out, num_nodes);
    } else {
        (void)hipMemsetAsync(d_out, 0, (size_t)out_size * sizeof(float), stream);
        scatter_device<<<(num_tnets + 255) / 256, 256, 0, stream>>>(
            beta, weights, (const long long*)flat_pins, pin2node, out, num_tnets);
    }
}

// Round 3
// 452.334 us; speedup vs baseline: 2.3960x; 1.3050x over previous
//
#include <hip/hip_runtime.h>
#include <stdint.h>

// PrecondTiming round 10. 3-pass + reduce:
//   K1: multisplit flat pins into NB1=40 pin-range bins (pin>>19, 2MB
//       pin2node slice per bin). Fewer bins than r7's 160 -> pass-E write
//       runs 205B -> ~820B, smaller scan, tighter caps.
//   K2: per pin-bin gather node=pin2node[pin] (2MB slice L2-resident via
//       XCD-affine bin-major mapping, r6-verified), multisplit by node
//       into NB2=64 bins (node>>14; ~512B write runs).
//   K3: per (bin, part) LDS accumulate, 8 parts/bin -> 512 blocks x 1024
//       thr = 2 blocks/CU. Tests latency vs DS-atomic theory for the
//       accumulate's stubborn ~150-200us (r7 scalar == r9 vectorized).
//   K4: out[n] = beta * sum_p partials[bin(n)*8+p][n&16383] (32MB, ~8us).
//
// Hard-won constraints (r8/r9):
//   - bulk global f32 atomics ~20G/s regardless of replication: NEVER
//     atomic the 16.8M stream (r8: 826us, WRITE 524MB).
//   - fused gather (no pin binning) is line-traffic-bound: 16.8M x 64B
//     = 1.05GB L2-miss at ~3.4TB/s ceiling = 370us (r9). Pin-binning
//     is mandatory for the gather to be L2-resident.

#define TILE 4096
#define THREADS 512
#define IPT  8                   // items per thread (TILE / THREADS)
#define NB1  40
#define SHIFT1 19                // pin >> 19 : 40 bins cover 20,971,520 pins
#define CAP1 430080              // 105 tiles; expected 419,430 (+16.6 sigma)
#define TPB1 105                 // CAP1 / TILE
#define NB2  64
#define SHIFT2 14                // node >> 14 : 64 bins cover 2^20 nodes
#define CAP2 270336              // expected 262,144 (+16 sigma)
#define ACC_NODES 16384          // nodes per node-bin
#define PARTS 8                  // accumulate blocks per node-bin
#define CHK (CAP2 / PARTS)       // 33,792 items per part
#define CTRL_BYTES 8192          // zeroed: cur1 @0 (40 ints), cur2 @2048 (64)

typedef unsigned long long item_t;   // low32 = key (pin or node), high32 = w
typedef int   int4_ev   __attribute__((ext_vector_type(4)));
typedef float float4_ev __attribute__((ext_vector_type(4)));
typedef unsigned long long ull2_ev __attribute__((ext_vector_type(2)));

__device__ __forceinline__ item_t pack_item(uint32_t key, float w) {
    return (item_t)key | ((item_t)__float_as_uint(w) << 32);
}

// ---- block-level tile multisplit (512 thr): counting-sort a tile in LDS,
// ---- write each bin's run contiguously to its global bin region.
// ---- Bins derived from key via >> shift (max 256 bins). 5 barriers total.
__device__ __forceinline__ void multisplit_flush(
    uint32_t (&key)[IPT], float (&wv)[IPT], int (&bin)[IPT],  // bin<0 = invalid
    int tile_cnt, int shift,
    int* __restrict__ gcur, item_t* __restrict__ gout, size_t cap)
{
    __shared__ int hist[256];
    __shared__ int basex[256];
    __shared__ int gbase[256];
    __shared__ int wsum[4];
    __shared__ item_t stage[TILE];
    const int t = threadIdx.x;

    if (t < 256) hist[t] = 0;
    __syncthreads();                                          // B1

    // pass A: per-bin rank via LDS atomics
    int rank[IPT];
#pragma unroll
    for (int k = 0; k < IPT; ++k)
        rank[k] = (bin[k] >= 0) ? atomicAdd(&hist[bin[k]], 1) : 0;
    __syncthreads();                                          // B2

    // pass B: wave-shuffle inclusive scan over 256 counters (waves 0-3)
    int val = (t < 256) ? hist[t] : 0;
    int inc = val;
#pragma unroll
    for (int d = 1; d < 64; d <<= 1) {
        int n = __shfl_up(inc, d, 64);
        if ((t & 63) >= d) inc += n;
    }
    if (t < 256 && (t & 63) == 63) wsum[t >> 6] = inc;
    __syncthreads();                                          // B3
    if (t < 256) {
        int w = t >> 6, prefix = 0;
        if (w > 0) prefix += wsum[0];
        if (w > 1) prefix += wsum[1];
        if (w > 2) prefix += wsum[2];
        basex[t] = prefix + inc - val;                        // exclusive base
        gbase[t] = (val > 0) ? atomicAdd(&gcur[t], val) : 0;  // reserve range
    }
    __syncthreads();                                          // B4

    // pass D: scatter into LDS in bin-sorted order
#pragma unroll
    for (int k = 0; k < IPT; ++k) {
        if (bin[k] >= 0)
            stage[basex[bin[k]] + rank[k]] = pack_item(key[k], wv[k]);
    }
    __syncthreads();                                          // B5

    // pass E: coalesced write-out; bin recomputed from stored key
    for (int j = t; j < tile_cnt; j += THREADS) {
        item_t e = stage[j];
        int b = (int)((uint32_t)(e & 0xffffffffull) >> shift);
        long long dst = (long long)gbase[b] + (j - basex[b]);
        if (dst >= 0 && dst < (long long)cap)
            __builtin_nontemporal_store(e, &gout[(size_t)b * cap + (size_t)dst]);
    }
}

// ---- K1: stream flat pins + weights (vectorized), partition by pin range ----
__global__ __launch_bounds__(THREADS, 8) void k1_partition_pins(
    const int* __restrict__ flat_pins, const float* __restrict__ weights,
    int* __restrict__ cur1, item_t* __restrict__ items1, int total)
{
    const int tileBase = blockIdx.x * TILE;
    const int t = threadIdx.x;
    const int base = tileBase + t * IPT;        // 8 consecutive items/thread
    uint32_t key[IPT]; float wv[IPT]; int bin[IPT];

    if (base + IPT <= total) {
        int4_ev   p[2];
        float4_ev w;
#pragma unroll
        for (int v = 0; v < 2; ++v)
            p[v] = __builtin_nontemporal_load((const int4_ev*)(flat_pins + base) + v);
        w = __builtin_nontemporal_load((const float4_ev*)(weights + (base >> 1)));
#pragma unroll
        for (int k = 0; k < IPT; ++k) {
            int pin = p[k >> 2][k & 3];
            key[k] = (uint32_t)pin;
            wv[k]  = w[(k >> 1) & 3];           // arc = (base+k)>>1: 4 consecutive
            bin[k] = pin >> SHIFT1;
        }
    } else {
#pragma unroll
        for (int k = 0; k < IPT; ++k) {
            int i = base + k;
            bool ok = i < total;
            int pin = ok ? flat_pins[i] : 0;
            key[k] = (uint32_t)pin;
            wv[k]  = ok ? weights[i >> 1] : 0.f;
            bin[k] = ok ? (pin >> SHIFT1) : -1;
        }
    }
    int cnt = min(TILE, total - tileBase);
    multisplit_flush(key, wv, bin, cnt, SHIFT1, cur1, items1, (size_t)CAP1);
}

// ---- K2: per pin-bin gather (L2-resident 2MB slice), partition by node ----
__global__ __launch_bounds__(THREADS, 8) void k2_gather_partition(
    const item_t* __restrict__ items1, const int* __restrict__ cur1,
    const int* __restrict__ pin2node,
    int* __restrict__ cur2, item_t* __restrict__ items2)
{
    // bin-major within each XCD residue (VERIFIED r6: keeps slices L2-resident)
    const int q = blockIdx.x;
    const int r = q & 7;
    const int s = q >> 3;
    const int bin  = r + 8 * (s / TPB1);        // 5 bin-groups per residue
    const int tile = s % TPB1;
    const int cnt = min(cur1[bin], (int)CAP1);
    const int tbase = tile * TILE;
    if (tbase >= cnt) return;

    const item_t* src = items1 + (size_t)bin * CAP1;
    const int t = threadIdx.x;
    const int base = tbase + t * IPT;
    uint32_t key[IPT]; float wv[IPT]; int b2[IPT];

    if (base + IPT <= cnt) {
        ull2_ev it[4];
#pragma unroll
        for (int v = 0; v < 4; ++v)
            it[v] = __builtin_nontemporal_load((const ull2_ev*)(src + base) + v);
#pragma unroll
        for (int k = 0; k < IPT; ++k) {
            item_t e = it[k >> 1][k & 1];
            int node = pin2node[(uint32_t)(e & 0xffffffffull)];  // L2-resident slice
            key[k] = (uint32_t)node;
            wv[k]  = __uint_as_float((uint32_t)(e >> 32));
            b2[k]  = node >> SHIFT2;
        }
    } else {
#pragma unroll
        for (int k = 0; k < IPT; ++k) {
            int i = base + k;
            bool ok = i < cnt;
            item_t e = ok ? src[i] : 0ull;
            int node = ok ? pin2node[(uint32_t)(e & 0xffffffffull)] : 0;
            key[k] = (uint32_t)node;
            wv[k]  = __uint_as_float((uint32_t)(e >> 32));
            b2[k]  = ok ? (node >> SHIFT2) : -1;
        }
    }
    int tcnt = min(TILE, cnt - tbase);
    multisplit_flush(key, wv, b2, tcnt, SHIFT2, cur2, items2, (size_t)CAP2);
}

// ---- K3: LDS accumulate, 8 part-blocks per node-bin (2 blocks/CU) ----
__global__ __launch_bounds__(1024, 8) void k3_accumulate_part(
    const item_t* __restrict__ items2, const int* __restrict__ cur2,
    float* __restrict__ partials)
{
    __shared__ float acc[ACC_NODES];
    const int b = blockIdx.x >> 3;               // node bin
    const int p = blockIdx.x & (PARTS - 1);      // part within bin
    const int t = threadIdx.x;
    for (int i = t; i < ACC_NODES; i += 1024) acc[i] = 0.f;
    __syncthreads();

    const int cnt = min(cur2[b], (int)CAP2);
    const int lo  = p * CHK;
    const int hi  = min(cnt, lo + CHK);
    const item_t* src = items2 + (size_t)b * CAP2;

    // 4 items (32B) per thread per iter; lo is 16B-aligned (CHK even)
    const int nv = (hi > lo) ? ((hi - lo) >> 2) : 0;
    for (int g = t; g < nv; g += 1024) {
        const item_t* pp = src + lo + ((size_t)g << 2);
        ull2_ev a0 = __builtin_nontemporal_load((const ull2_ev*)pp);
        ull2_ev a1 = __builtin_nontemporal_load((const ull2_ev*)pp + 1);
#pragma unroll
        for (int k = 0; k < 2; ++k) {
            item_t e0 = a0[k], e1 = a1[k];
            atomicAdd(&acc[(uint32_t)(e0 & 0xffffffffull) & (ACC_NODES - 1)],
                      __uint_as_float((uint32_t)(e0 >> 32)));
            atomicAdd(&acc[(uint32_t)(e1 & 0xffffffffull) & (ACC_NODES - 1)],
                      __uint_as_float((uint32_t)(e1 >> 32)));
        }
    }
    for (int i = lo + (nv << 2) + t; i < hi; i += 1024) {
        item_t e = __builtin_nontemporal_load(&src[i]);
        atomicAdd(&acc[(uint32_t)(e & 0xffffffffull) & (ACC_NODES - 1)],
                  __uint_as_float((uint32_t)(e >> 32)));
    }
    __syncthreads();

    float* __restrict__ dst = partials + (size_t)blockIdx.x * ACC_NODES;
    for (int i = t; i < ACC_NODES; i += 1024) dst[i] = acc[i];
}

// ---- K4: out[n] = beta * sum over PARTS partials (32MB streamed) ----
__global__ __launch_bounds__(256) void k4_reduce(
    const float* __restrict__ partials, const float* __restrict__ beta,
    float* __restrict__ out, int num_nodes)
{
    const float bt = beta[0];
    const int n = (blockIdx.x * 256 + threadIdx.x) << 2;
    if (n + 3 < num_nodes) {
        const int b   = n >> SHIFT2;
        const int off = n & (ACC_NODES - 1);
        const float* base = partials + ((size_t)b * PARTS) * ACC_NODES + off;
        float4_ev s = {0.f, 0.f, 0.f, 0.f};
#pragma unroll
        for (int p = 0; p < PARTS; ++p)
            s += *(const float4_ev*)(base + (size_t)p * ACC_NODES);
        *(float4_ev*)(out + n) = s * bt;
    } else {
        for (int k = 0; k < 4; ++k) {
            int nn = n + k;
            if (nn < num_nodes) {
                const int b   = nn >> SHIFT2;
                const int off = nn & (ACC_NODES - 1);
                float s = 0.f;
#pragma unroll
                for (int p = 0; p < PARTS; ++p)
                    s += partials[((size_t)b * PARTS + p) * ACC_NODES + off];
                out[nn] = s * bt;
            }
        }
    }
}

// ---- fallback (round-1, known-good ~830us): device-scope atomics ----
__global__ __launch_bounds__(256) void scatter_device(
    const float* __restrict__ beta, const float* __restrict__ tnet_weights,
    const long long* __restrict__ pin_pairs, const int* __restrict__ pin2node_map,
    float* __restrict__ out, int num_tnets)
{
    int t = blockIdx.x * blockDim.x + threadIdx.x;
    if (t >= num_tnets) return;
    long long pp = pin_pairs[t];
    float w = tnet_weights[t] * beta[0];
    atomicAdd(&out[pin2node_map[(int)(pp & 0xffffffffLL)]], w);
    atomicAdd(&out[pin2node_map[(int)(pp >> 32)]], w);
}

extern "C" void kernel_launch(void* const* d_in, const int* in_sizes, int n_in,
                              void* d_out, int out_size, void* d_ws, size_t ws_size,
                              hipStream_t stream) {
    const float* beta         = (const float*)d_in[0];
    const float* weights      = (const float*)d_in[1];
    const int*   flat_pins    = (const int*)d_in[2];
    const int*   pin2node     = (const int*)d_in[3];
    float* out = (float*)d_out;

    const int num_tnets = in_sizes[1];
    const int total     = in_sizes[2];       // 2 * num_tnets flat pin slots
    const int num_nodes = out_size;

    const size_t items1Bytes = (size_t)NB1 * CAP1 * sizeof(item_t);   // 137.6 MB
    const size_t items2Bytes = (size_t)NB2 * CAP2 * sizeof(item_t);   // 138.4 MB
    const size_t partBytes   = (size_t)NB2 * PARTS * ACC_NODES * sizeof(float); // 32 MB

    int* cur1 = (int*)d_ws;                          // bytes [0, 160)
    int* cur2 = (int*)((char*)d_ws + 2048);          // bytes [2048, 2304)
    const int gridTiles = (total + TILE - 1) / TILE;

    if (ws_size >= CTRL_BYTES + items1Bytes + items2Bytes + partBytes) {
        item_t* items1 = (item_t*)((char*)d_ws + CTRL_BYTES);
        item_t* items2 = (item_t*)((char*)d_ws + CTRL_BYTES + items1Bytes);
        float*  partials = (float*)((char*)d_ws + CTRL_BYTES + items1Bytes + items2Bytes);
        (void)hipMemsetAsync(d_ws, 0, CTRL_BYTES, stream);
        k1_partition_pins<<<gridTiles, THREADS, 0, stream>>>(
            flat_pins, weights, cur1, items1, total);
        k2_gather_partition<<<NB1 * TPB1, THREADS, 0, stream>>>(
            items1, cur1, pin2node, cur2, items2);
        k3_accumulate_part<<<NB2 * PARTS, 1024, 0, stream>>>(
            items2, cur2, partials);
        const int i4slots = (num_nodes + 3) / 4;
        k4_reduce<<<(i4slots + 255) / 256, 256, 0, stream>>>(
            partials, beta, out, num_nodes);
    } else {
        (void)hipMemsetAsync(d_out, 0, (size_t)out_size * sizeof(float), stream);
        scatter_device<<<(num_tnets + 255) / 256, 256, 0, stream>>>(
            beta, weights, (const long long*)flat_pins, pin2node, out, num_tnets);
    }
}

// Round 4
// 434.447 us; speedup vs baseline: 2.4947x; 1.0412x over previous
//
#include <hip/hip_runtime.h>
#include <stdint.h>

// PrecondTiming round 11. 3-pass + reduce, per-XCD-residue reservation
// counters (THE change this round):
//   r10 diagnosis: all passes ~3x over issue/BW floor with VALU 9%,
//   HBM 23%, occupancy 77% -> all resident blocks simultaneously
//   stalled. Cause: range-reservation atomicAdd(&gcur[bin]) -- 40 (K1)
//   / 64 (K2) counters packed into 3-4 cache lines, 164K-268K
//   device-wide same-line atomics; each block's pass-E waits (via the
//   pre-barrier vmcnt(0) drain) on its slowest contended atomic.
//   Queue depth ~67-131K per line ~= the entire kernel duration.
// Fix: counters cur[bin][residue] (residue = blockIdx&7), ONE PER 64B
//   LINE; item regions split into per-(bin,residue) sub-regions with
//   static +11sigma caps. Contention per line: 560-1024 atomics spread
//   over the kernel (queue depth ~1). K3 parts == writer residues.
//
// Hard-won constraints (r8/r9):
//   - bulk global f32 atomics ~20G/s regardless of replication: NEVER
//     atomic the 16.8M item stream (r8: 826us, WRITE 524MB).
//   - fused gather (no pin binning) is line-traffic-bound: 16.8M x 64B
//     = 1.05GB L2-miss at ~3.4TB/s = 370us (r9). Pin-binning mandatory.

#define TILE 4096
#define THREADS 512
#define IPT  8                   // items per thread (TILE / THREADS)
#define NB1  40
#define SHIFT1 19                // pin >> 19 : 40 bins cover 20,971,520 pins
#define CAP1R 55296              // per (bin,residue); expected 52,429 (+12.7s)
#define TPB1R 14                 // ceil(CAP1R / TILE)
#define NB2  64
#define SHIFT2 14                // node >> 14 : 64 bins cover 2^20 nodes
#define CAP2R 34816              // per (bin,residue); expected 32,768 (+11.4s)
#define ACC_NODES 16384          // nodes per node-bin
#define PARTS 8                  // accumulate blocks per node-bin = residues
#define CLINE_INTS 16            // one counter per 64B cache line
#define CTRL_BYTES 65536         // ctrl1 @0 (40*8 lines), ctrl2 @32768 (64*8)

typedef unsigned long long item_t;   // low32 = key (pin or node), high32 = w
typedef int   int4_ev   __attribute__((ext_vector_type(4)));
typedef float float4_ev __attribute__((ext_vector_type(4)));
typedef unsigned long long ull2_ev __attribute__((ext_vector_type(2)));

__device__ __forceinline__ item_t pack_item(uint32_t key, float w) {
    return (item_t)key | ((item_t)__float_as_uint(w) << 32);
}

// ---- block-level tile multisplit (512 thr): counting-sort a tile in LDS,
// ---- write each bin's run contiguously into this residue's sub-region.
// ---- Counter for bin b: gcur[b * gcur_stride] (one per 64B line).
// ---- Output for bin b: gout[b * bin_stride + dst], dst < cap.
__device__ __forceinline__ void multisplit_flush(
    uint32_t (&key)[IPT], float (&wv)[IPT], int (&bin)[IPT],  // bin<0 = invalid
    int tile_cnt, int shift,
    int* __restrict__ gcur, int gcur_stride,
    item_t* __restrict__ gout, size_t bin_stride, size_t cap)
{
    __shared__ int hist[256];
    __shared__ int basex[256];
    __shared__ int gbase[256];
    __shared__ int wsum[4];
    __shared__ item_t stage[TILE];
    const int t = threadIdx.x;

    if (t < 256) hist[t] = 0;
    __syncthreads();                                          // B1

    // pass A: per-bin rank via LDS atomics
    int rank[IPT];
#pragma unroll
    for (int k = 0; k < IPT; ++k)
        rank[k] = (bin[k] >= 0) ? atomicAdd(&hist[bin[k]], 1) : 0;
    __syncthreads();                                          // B2

    // pass B: wave-shuffle inclusive scan over 256 counters (waves 0-3)
    int val = (t < 256) ? hist[t] : 0;
    int inc = val;
#pragma unroll
    for (int d = 1; d < 64; d <<= 1) {
        int n = __shfl_up(inc, d, 64);
        if ((t & 63) >= d) inc += n;
    }
    if (t < 256 && (t & 63) == 63) wsum[t >> 6] = inc;
    __syncthreads();                                          // B3
    if (t < 256) {
        int w = t >> 6, prefix = 0;
        if (w > 0) prefix += wsum[0];
        if (w > 1) prefix += wsum[1];
        if (w > 2) prefix += wsum[2];
        basex[t] = prefix + inc - val;                        // exclusive base
        gbase[t] = (val > 0) ? atomicAdd(&gcur[t * gcur_stride], val) : 0;
    }
    __syncthreads();                                          // B4

    // pass D: scatter into LDS in bin-sorted order
#pragma unroll
    for (int k = 0; k < IPT; ++k) {
        if (bin[k] >= 0)
            stage[basex[bin[k]] + rank[k]] = pack_item(key[k], wv[k]);
    }
    __syncthreads();                                          // B5

    // pass E: coalesced write-out; bin recomputed from stored key
    for (int j = t; j < tile_cnt; j += THREADS) {
        item_t e = stage[j];
        int b = (int)((uint32_t)(e & 0xffffffffull) >> shift);
        long long dst = (long long)gbase[b] + (j - basex[b]);
        if (dst >= 0 && dst < (long long)cap)
            __builtin_nontemporal_store(e, &gout[(size_t)b * bin_stride + (size_t)dst]);
    }
}

// ---- K1: stream flat pins + weights (vectorized), partition by pin range ----
__global__ __launch_bounds__(THREADS, 8) void k1_partition_pins(
    const int* __restrict__ flat_pins, const float* __restrict__ weights,
    int* __restrict__ ctrl1, item_t* __restrict__ items1, int total)
{
    const int tileBase = blockIdx.x * TILE;
    const int r = blockIdx.x & 7;               // XCD residue class
    const int t = threadIdx.x;
    const int base = tileBase + t * IPT;        // 8 consecutive items/thread
    uint32_t key[IPT]; float wv[IPT]; int bin[IPT];

    if (base + IPT <= total) {
        int4_ev   p[2];
        float4_ev w;
#pragma unroll
        for (int v = 0; v < 2; ++v)
            p[v] = __builtin_nontemporal_load((const int4_ev*)(flat_pins + base) + v);
        w = __builtin_nontemporal_load((const float4_ev*)(weights + (base >> 1)));
#pragma unroll
        for (int k = 0; k < IPT; ++k) {
            int pin = p[k >> 2][k & 3];
            key[k] = (uint32_t)pin;
            wv[k]  = w[(k >> 1) & 3];           // arc = (base+k)>>1: 4 consecutive
            bin[k] = pin >> SHIFT1;
        }
    } else {
#pragma unroll
        for (int k = 0; k < IPT; ++k) {
            int i = base + k;
            bool ok = i < total;
            int pin = ok ? flat_pins[i] : 0;
            key[k] = (uint32_t)pin;
            wv[k]  = ok ? weights[i >> 1] : 0.f;
            bin[k] = ok ? (pin >> SHIFT1) : -1;
        }
    }
    int cnt = min(TILE, total - tileBase);
    multisplit_flush(key, wv, bin, cnt, SHIFT1,
                     ctrl1 + r * CLINE_INTS, 8 * CLINE_INTS,
                     items1 + (size_t)r * CAP1R, (size_t)8 * CAP1R,
                     (size_t)CAP1R);
}

// ---- K2: per pin-bin gather (L2-resident 2MB slice), partition by node ----
__global__ __launch_bounds__(THREADS, 8) void k2_gather_partition(
    const item_t* __restrict__ items1, const int* __restrict__ ctrl1,
    const int* __restrict__ pin2node,
    int* __restrict__ ctrl2, item_t* __restrict__ items2)
{
    // bin-major within each XCD residue (VERIFIED r6: keeps slices L2-resident)
    const int q = blockIdx.x;
    const int r2 = q & 7;                        // this block's residue class
    const int s  = q >> 3;                       // 0..559
    const int g    = s / (8 * TPB1R);            // 0..4  bin-group
    const int rem  = s % (8 * TPB1R);
    const int r_w  = rem / TPB1R;                // writer residue of sub-region
    const int tile = rem % TPB1R;
    const int bin  = r2 + 8 * g;                 // pin-bin: same-XCD share slice
    const int cnt = min(ctrl1[(bin * 8 + r_w) * CLINE_INTS], (int)CAP1R);
    const int tbase = tile * TILE;
    if (tbase >= cnt) return;

    const item_t* src = items1 + ((size_t)bin * 8 + (size_t)r_w) * CAP1R;
    const int t = threadIdx.x;
    const int base = tbase + t * IPT;
    uint32_t key[IPT]; float wv[IPT]; int b2[IPT];

    if (base + IPT <= cnt) {
        ull2_ev it[4];
#pragma unroll
        for (int v = 0; v < 4; ++v)
            it[v] = __builtin_nontemporal_load((const ull2_ev*)(src + base) + v);
#pragma unroll
        for (int k = 0; k < IPT; ++k) {
            item_t e = it[k >> 1][k & 1];
            int node = pin2node[(uint32_t)(e & 0xffffffffull)];  // L2-resident slice
            key[k] = (uint32_t)node;
            wv[k]  = __uint_as_float((uint32_t)(e >> 32));
            b2[k]  = node >> SHIFT2;
        }
    } else {
#pragma unroll
        for (int k = 0; k < IPT; ++k) {
            int i = base + k;
            bool ok = i < cnt;
            item_t e = ok ? src[i] : 0ull;
            int node = ok ? pin2node[(uint32_t)(e & 0xffffffffull)] : 0;
            key[k] = (uint32_t)node;
            wv[k]  = __uint_as_float((uint32_t)(e >> 32));
            b2[k]  = ok ? (node >> SHIFT2) : -1;
        }
    }
    int tcnt = min(TILE, cnt - tbase);
    multisplit_flush(key, wv, b2, tcnt, SHIFT2,
                     ctrl2 + r2 * CLINE_INTS, 8 * CLINE_INTS,
                     items2 + (size_t)r2 * CAP2R, (size_t)8 * CAP2R,
                     (size_t)CAP2R);
}

// ---- K3: LDS accumulate, one block per (node-bin, residue) sub-region ----
__global__ __launch_bounds__(1024, 8) void k3_accumulate_part(
    const item_t* __restrict__ items2, const int* __restrict__ ctrl2,
    float* __restrict__ partials)
{
    __shared__ float acc[ACC_NODES];
    const int b = blockIdx.x >> 3;               // node bin
    const int p = blockIdx.x & (PARTS - 1);      // residue sub-region
    const int t = threadIdx.x;
    for (int i = t; i < ACC_NODES; i += 1024) acc[i] = 0.f;
    __syncthreads();

    const int cnt = min(ctrl2[(b * 8 + p) * CLINE_INTS], (int)CAP2R);
    const item_t* src = items2 + ((size_t)b * 8 + (size_t)p) * CAP2R;

    // 4 items (32B) per thread per iter
    const int nv = cnt >> 2;
    for (int g = t; g < nv; g += 1024) {
        const item_t* pp = src + ((size_t)g << 2);
        ull2_ev a0 = __builtin_nontemporal_load((const ull2_ev*)pp);
        ull2_ev a1 = __builtin_nontemporal_load((const ull2_ev*)pp + 1);
#pragma unroll
        for (int k = 0; k < 2; ++k) {
            item_t e0 = a0[k], e1 = a1[k];
            atomicAdd(&acc[(uint32_t)(e0 & 0xffffffffull) & (ACC_NODES - 1)],
                      __uint_as_float((uint32_t)(e0 >> 32)));
            atomicAdd(&acc[(uint32_t)(e1 & 0xffffffffull) & (ACC_NODES - 1)],
                      __uint_as_float((uint32_t)(e1 >> 32)));
        }
    }
    for (int i = (nv << 2) + t; i < cnt; i += 1024) {
        item_t e = __builtin_nontemporal_load(&src[i]);
        atomicAdd(&acc[(uint32_t)(e & 0xffffffffull) & (ACC_NODES - 1)],
                  __uint_as_float((uint32_t)(e >> 32)));
    }
    __syncthreads();

    float* __restrict__ dst = partials + (size_t)blockIdx.x * ACC_NODES;
    for (int i = t; i < ACC_NODES; i += 1024) dst[i] = acc[i];
}

// ---- K4: out[n] = beta * sum over PARTS partials (32MB streamed) ----
__global__ __launch_bounds__(256) void k4_reduce(
    const float* __restrict__ partials, const float* __restrict__ beta,
    float* __restrict__ out, int num_nodes)
{
    const float bt = beta[0];
    const int n = (blockIdx.x * 256 + threadIdx.x) << 2;
    if (n + 3 < num_nodes) {
        const int b   = n >> SHIFT2;
        const int off = n & (ACC_NODES - 1);
        const float* base = partials + ((size_t)b * PARTS) * ACC_NODES + off;
        float4_ev s = {0.f, 0.f, 0.f, 0.f};
#pragma unroll
        for (int p = 0; p < PARTS; ++p)
            s += *(const float4_ev*)(base + (size_t)p * ACC_NODES);
        *(float4_ev*)(out + n) = s * bt;
    } else {
        for (int k = 0; k < 4; ++k) {
            int nn = n + k;
            if (nn < num_nodes) {
                const int b   = nn >> SHIFT2;
                const int off = nn & (ACC_NODES - 1);
                float s = 0.f;
#pragma unroll
                for (int p = 0; p < PARTS; ++p)
                    s += partials[((size_t)b * PARTS + p) * ACC_NODES + off];
                out[nn] = s * bt;
            }
        }
    }
}

// ---- fallback (round-1, known-good ~830us): device-scope atomics ----
__global__ __launch_bounds__(256) void scatter_device(
    const float* __restrict__ beta, const float* __restrict__ tnet_weights,
    const long long* __restrict__ pin_pairs, const int* __restrict__ pin2node_map,
    float* __restrict__ out, int num_tnets)
{
    int t = blockIdx.x * blockDim.x + threadIdx.x;
    if (t >= num_tnets) return;
    long long pp = pin_pairs[t];
    float w = tnet_weights[t] * beta[0];
    atomicAdd(&out[pin2node_map[(int)(pp & 0xffffffffLL)]], w);
    atomicAdd(&out[pin2node_map[(int)(pp >> 32)]], w);
}

extern "C" void kernel_launch(void* const* d_in, const int* in_sizes, int n_in,
                              void* d_out, int out_size, void* d_ws, size_t ws_size,
                              hipStream_t stream) {
    const float* beta         = (const float*)d_in[0];
    const float* weights      = (const float*)d_in[1];
    const int*   flat_pins    = (const int*)d_in[2];
    const int*   pin2node     = (const int*)d_in[3];
    float* out = (float*)d_out;

    const int num_tnets = in_sizes[1];
    const int total     = in_sizes[2];       // 2 * num_tnets flat pin slots
    const int num_nodes = out_size;

    const size_t items1Bytes = (size_t)NB1 * 8 * CAP1R * sizeof(item_t);  // 141.6 MB
    const size_t items2Bytes = (size_t)NB2 * 8 * CAP2R * sizeof(item_t);  // 142.6 MB
    const size_t partBytes   = (size_t)NB2 * PARTS * ACC_NODES * sizeof(float); // 32 MB

    int* ctrl1 = (int*)d_ws;                           // 40*8 padded counters
    int* ctrl2 = (int*)((char*)d_ws + 32768);          // 64*8 padded counters
    const int gridTiles = (total + TILE - 1) / TILE;

    if (ws_size >= CTRL_BYTES + items1Bytes + items2Bytes + partBytes) {
        item_t* items1 = (item_t*)((char*)d_ws + CTRL_BYTES);
        item_t* items2 = (item_t*)((char*)d_ws + CTRL_BYTES + items1Bytes);
        float*  partials = (float*)((char*)d_ws + CTRL_BYTES + items1Bytes + items2Bytes);
        (void)hipMemsetAsync(d_ws, 0, CTRL_BYTES, stream);
        k1_partition_pins<<<gridTiles, THREADS, 0, stream>>>(
            flat_pins, weights, ctrl1, items1, total);
        k2_gather_partition<<<NB1 * 8 * TPB1R, THREADS, 0, stream>>>(
            items1, ctrl1, pin2node, ctrl2, items2);
        k3_accumulate_part<<<NB2 * PARTS, 1024, 0, stream>>>(
            items2, ctrl2, partials);
        const int i4slots = (num_nodes + 3) / 4;
        k4_reduce<<<(i4slots + 255) / 256, 256, 0, stream>>>(
            partials, beta, out, num_nodes);
    } else {
        (void)hipMemsetAsync(d_out, 0, (size_t)out_size * sizeof(float), stream);
        scatter_device<<<(num_tnets + 255) / 256, 256, 0, stream>>>(
            beta, weights, (const long long*)flat_pins, pin2node, out, num_tnets);
    }
}

// Round 5
// 433.134 us; speedup vs baseline: 2.5022x; 1.0030x over previous
//
#include <hip/hip_runtime.h>
#include <stdint.h>

// PrecondTiming round 12. 3-pass + reduce. THE change this round:
// de-spill multisplit_flush.
//   r11 evidence: K2 unchanged (148->155) by counter-padding; K1/K2 floor
//   ~150us survives barriers/bins/contention changes. VALU 9%, HBM 23%,
//   occupancy 68%, all pipes idle. VGPR_Count=24 but the old multisplit
//   kept key[8]+wv[8]+rank[8] (+addresses) live across B2..B5 = live set
//   ~40 > 24 -> compiler was SPILLING to scratch under the
//   __launch_bounds__(512,8) 64-VGPR cap. Scratch vmem is invisible in
//   FETCH/WRITE (L2-backed) and VALUBusy (pure waits) -- fits every
//   symptom, and poisons K1+K2 identically (same function).
// Fix: items packed ONCE into item_t e[8] (16 regs; bin recomputed by
//   shift), ranks packed 2-per-u32 (4 regs), gbase+basex merged into one
//   packed ull LDS array (also 1 ds_read_b64/item in pass E, not 2
//   ds_read_b32). Live set ~28 regs -> fits 64-cap, no spill, occupancy
//   unchanged (4 blocks/CU). VGPR_Count is the witness: expect 24 -> 32+.
//
// Hard-won constraints (r8/r9):
//   - bulk global f32 atomics ~20G/s: NEVER atomic the 16.8M stream
//     (r8: 826us). - unbinned gather = 1.05GB line traffic at ~2.8TB/s
//     = 370us (r9): pin-binning mandatory.

#define TILE 4096
#define THREADS 512
#define IPT  8                   // items per thread (TILE / THREADS)
#define NB1  40
#define SHIFT1 19                // pin >> 19 : 40 bins cover 20,971,520 pins
#define CAP1R 55296              // per (bin,residue); expected 52,429 (+12.7s)
#define TPB1R 14                 // ceil(CAP1R / TILE)
#define NB2  64
#define SHIFT2 14                // node >> 14 : 64 bins cover 2^20 nodes
#define CAP2R 34816              // per (bin,residue); expected 32,768 (+11.4s)
#define ACC_NODES 16384          // nodes per node-bin
#define PARTS 8                  // accumulate blocks per node-bin = residues
#define CLINE_INTS 16            // one counter per 64B cache line
#define CTRL_BYTES 65536         // ctrl1 @0 (40*8 lines), ctrl2 @32768 (64*8)

typedef unsigned long long item_t;   // low32 = key (pin or node), high32 = w
typedef int   int4_ev   __attribute__((ext_vector_type(4)));
typedef float float4_ev __attribute__((ext_vector_type(4)));
typedef unsigned long long ull2_ev __attribute__((ext_vector_type(2)));

__device__ __forceinline__ item_t pack_item(uint32_t key, float w) {
    return (item_t)key | ((item_t)__float_as_uint(w) << 32);
}

// ---- block-level tile multisplit (512 thr): counting-sort a tile in LDS,
// ---- write each bin's run contiguously into this residue's sub-region.
// ---- Items arrive PACKED in e[]; first vcnt of each thread's e[] valid.
// ---- Live set across barriers: e[8] + rankp[4] + ~6 = ~28 VGPRs (no spill).
__device__ __forceinline__ void multisplit_flush(
    item_t (&e)[IPT], int vcnt, int tile_cnt, int shift,
    int* __restrict__ gcur, int gcur_stride,
    item_t* __restrict__ gout, size_t bin_stride, size_t cap)
{
    __shared__ int hist[256];
    __shared__ unsigned long long combo[256];   // hi32 = gbase, lo32 = basex
    __shared__ int wsum[4];
    __shared__ item_t stage[TILE];
    const int t = threadIdx.x;

    if (t < 256) hist[t] = 0;
    __syncthreads();                                          // B1

    // pass A: per-bin rank via LDS atomics; ranks packed 2-per-u32 (<4096)
    uint32_t rankp[IPT / 2];
#pragma unroll
    for (int k = 0; k < IPT; ++k) {
        int b = (int)((uint32_t)e[k] >> shift);
        uint32_t r = (k < vcnt) ? (uint32_t)atomicAdd(&hist[b], 1) : 0u;
        if ((k & 1) == 0) rankp[k >> 1] = r;
        else              rankp[k >> 1] |= (r << 16);
    }
    __syncthreads();                                          // B2

    // pass B: wave-shuffle inclusive scan over 256 counters (waves 0-3)
    int val = (t < 256) ? hist[t] : 0;
    int inc = val;
#pragma unroll
    for (int d = 1; d < 64; d <<= 1) {
        int n = __shfl_up(inc, d, 64);
        if ((t & 63) >= d) inc += n;
    }
    if (t < 256 && (t & 63) == 63) wsum[t >> 6] = inc;
    __syncthreads();                                          // B3
    if (t < 256) {
        int w = t >> 6, prefix = 0;
        if (w > 0) prefix += wsum[0];
        if (w > 1) prefix += wsum[1];
        if (w > 2) prefix += wsum[2];
        int bx = prefix + inc - val;                          // exclusive base
        int gb = (val > 0) ? atomicAdd(&gcur[t * gcur_stride], val) : 0;
        combo[t] = ((unsigned long long)(uint32_t)gb << 32) | (uint32_t)bx;
    }
    __syncthreads();                                          // B4

    // pass D: scatter into LDS in bin-sorted order
#pragma unroll
    for (int k = 0; k < IPT; ++k) {
        if (k < vcnt) {
            int b = (int)((uint32_t)e[k] >> shift);
            int r = (int)((rankp[k >> 1] >> ((k & 1) * 16)) & 0xffffu);
            stage[(int)((uint32_t)combo[b]) + r] = e[k];
        }
    }
    __syncthreads();                                          // B5

    // pass E: coalesced write-out; bin recomputed from stored key
    for (int j = t; j < tile_cnt; j += THREADS) {
        item_t ev = stage[j];
        int b = (int)((uint32_t)(ev & 0xffffffffull) >> shift);
        unsigned long long c = combo[b];
        long long dst = (long long)(int)(c >> 32) + (j - (int)(uint32_t)c);
        if (dst >= 0 && dst < (long long)cap)
            __builtin_nontemporal_store(ev, &gout[(size_t)b * bin_stride + (size_t)dst]);
    }
}

// ---- K1: stream flat pins + weights (vectorized), partition by pin range ----
__global__ __launch_bounds__(THREADS, 8) void k1_partition_pins(
    const int* __restrict__ flat_pins, const float* __restrict__ weights,
    int* __restrict__ ctrl1, item_t* __restrict__ items1, int total)
{
    const int tileBase = blockIdx.x * TILE;
    const int r = blockIdx.x & 7;               // XCD residue class
    const int t = threadIdx.x;
    const int base = tileBase + t * IPT;        // 8 consecutive items/thread
    item_t e[IPT];
    int vcnt;

    if (base + IPT <= total) {
        vcnt = IPT;
        int4_ev   p[2];
        float4_ev w;
#pragma unroll
        for (int v = 0; v < 2; ++v)
            p[v] = __builtin_nontemporal_load((const int4_ev*)(flat_pins + base) + v);
        w = __builtin_nontemporal_load((const float4_ev*)(weights + (base >> 1)));
#pragma unroll
        for (int k = 0; k < IPT; ++k)
            e[k] = pack_item((uint32_t)p[k >> 2][k & 3], w[(k >> 1) & 3]);
    } else {
        int rem = total - base;
        vcnt = rem < 0 ? 0 : (rem > IPT ? IPT : rem);
#pragma unroll
        for (int k = 0; k < IPT; ++k) {
            int i = base + k;
            bool ok = i < total;
            e[k] = ok ? pack_item((uint32_t)flat_pins[i], weights[i >> 1]) : 0ull;
        }
    }
    int cnt = min(TILE, total - tileBase);
    multisplit_flush(e, vcnt, cnt, SHIFT1,
                     ctrl1 + r * CLINE_INTS, 8 * CLINE_INTS,
                     items1 + (size_t)r * CAP1R, (size_t)8 * CAP1R,
                     (size_t)CAP1R);
}

// ---- K2: per pin-bin gather (L2-resident 2MB slice), partition by node ----
__global__ __launch_bounds__(THREADS, 8) void k2_gather_partition(
    const item_t* __restrict__ items1, const int* __restrict__ ctrl1,
    const int* __restrict__ pin2node,
    int* __restrict__ ctrl2, item_t* __restrict__ items2)
{
    // bin-major within each XCD residue (VERIFIED r6: keeps slices L2-resident)
    const int q = blockIdx.x;
    const int r2 = q & 7;                        // this block's residue class
    const int s  = q >> 3;                       // 0..559
    const int g    = s / (8 * TPB1R);            // 0..4  bin-group
    const int rem  = s % (8 * TPB1R);
    const int r_w  = rem / TPB1R;                // writer residue of sub-region
    const int tile = rem % TPB1R;
    const int bin  = r2 + 8 * g;                 // pin-bin: same-XCD share slice
    const int cnt = min(ctrl1[(bin * 8 + r_w) * CLINE_INTS], (int)CAP1R);
    const int tbase = tile * TILE;
    if (tbase >= cnt) return;

    const item_t* src = items1 + ((size_t)bin * 8 + (size_t)r_w) * CAP1R;
    const int t = threadIdx.x;
    const int base = tbase + t * IPT;
    item_t e[IPT];
    int vcnt;

    if (base + IPT <= cnt) {
        vcnt = IPT;
        ull2_ev it[4];
#pragma unroll
        for (int v = 0; v < 4; ++v)
            it[v] = __builtin_nontemporal_load((const ull2_ev*)(src + base) + v);
#pragma unroll
        for (int k = 0; k < IPT; ++k) {
            item_t ev = it[k >> 1][k & 1];
            int node = pin2node[(uint32_t)(ev & 0xffffffffull)];  // L2-resident slice
            e[k] = (ev & 0xffffffff00000000ull) | (uint32_t)node;
        }
    } else {
        int rem2 = cnt - base;
        vcnt = rem2 < 0 ? 0 : (rem2 > IPT ? IPT : rem2);
#pragma unroll
        for (int k = 0; k < IPT; ++k) {
            int i = base + k;
            bool ok = i < cnt;
            item_t ev = ok ? src[i] : 0ull;
            int node = ok ? pin2node[(uint32_t)(ev & 0xffffffffull)] : 0;
            e[k] = (ev & 0xffffffff00000000ull) | (uint32_t)node;
        }
    }
    int tcnt = min(TILE, cnt - tbase);
    multisplit_flush(e, vcnt, tcnt, SHIFT2,
                     ctrl2 + r2 * CLINE_INTS, 8 * CLINE_INTS,
                     items2 + (size_t)r2 * CAP2R, (size_t)8 * CAP2R,
                     (size_t)CAP2R);
}

// ---- K3: LDS accumulate, one block per (node-bin, residue) sub-region ----
__global__ __launch_bounds__(1024, 8) void k3_accumulate_part(
    const item_t* __restrict__ items2, const int* __restrict__ ctrl2,
    float* __restrict__ partials)
{
    __shared__ float acc[ACC_NODES];
    const int b = blockIdx.x >> 3;               // node bin
    const int p = blockIdx.x & (PARTS - 1);      // residue sub-region
    const int t = threadIdx.x;
    for (int i = t; i < ACC_NODES; i += 1024) acc[i] = 0.f;
    __syncthreads();

    const int cnt = min(ctrl2[(b * 8 + p) * CLINE_INTS], (int)CAP2R);
    const item_t* src = items2 + ((size_t)b * 8 + (size_t)p) * CAP2R;

    // 4 items (32B) per thread per iter
    const int nv = cnt >> 2;
    for (int g = t; g < nv; g += 1024) {
        const item_t* pp = src + ((size_t)g << 2);
        ull2_ev a0 = __builtin_nontemporal_load((const ull2_ev*)pp);
        ull2_ev a1 = __builtin_nontemporal_load((const ull2_ev*)pp + 1);
#pragma unroll
        for (int k = 0; k < 2; ++k) {
            item_t e0 = a0[k], e1 = a1[k];
            atomicAdd(&acc[(uint32_t)(e0 & 0xffffffffull) & (ACC_NODES - 1)],
                      __uint_as_float((uint32_t)(e0 >> 32)));
            atomicAdd(&acc[(uint32_t)(e1 & 0xffffffffull) & (ACC_NODES - 1)],
                      __uint_as_float((uint32_t)(e1 >> 32)));
        }
    }
    for (int i = (nv << 2) + t; i < cnt; i += 1024) {
        item_t e = __builtin_nontemporal_load(&src[i]);
        atomicAdd(&acc[(uint32_t)(e & 0xffffffffull) & (ACC_NODES - 1)],
                  __uint_as_float((uint32_t)(e >> 32)));
    }
    __syncthreads();

    float* __restrict__ dst = partials + (size_t)blockIdx.x * ACC_NODES;
    for (int i = t; i < ACC_NODES; i += 1024) dst[i] = acc[i];
}

// ---- K4: out[n] = beta * sum over PARTS partials (32MB streamed) ----
__global__ __launch_bounds__(256) void k4_reduce(
    const float* __restrict__ partials, const float* __restrict__ beta,
    float* __restrict__ out, int num_nodes)
{
    const float bt = beta[0];
    const int n = (blockIdx.x * 256 + threadIdx.x) << 2;
    if (n + 3 < num_nodes) {
        const int b   = n >> SHIFT2;
        const int off = n & (ACC_NODES - 1);
        const float* base = partials + ((size_t)b * PARTS) * ACC_NODES + off;
        float4_ev s = {0.f, 0.f, 0.f, 0.f};
#pragma unroll
        for (int p = 0; p < PARTS; ++p)
            s += *(const float4_ev*)(base + (size_t)p * ACC_NODES);
        *(float4_ev*)(out + n) = s * bt;
    } else {
        for (int k = 0; k < 4; ++k) {
            int nn = n + k;
            if (nn < num_nodes) {
                const int b   = nn >> SHIFT2;
                const int off = nn & (ACC_NODES - 1);
                float s = 0.f;
#pragma unroll
                for (int p = 0; p < PARTS; ++p)
                    s += partials[((size_t)b * PARTS + p) * ACC_NODES + off];
                out[nn] = s * bt;
            }
        }
    }
}

// ---- fallback (round-1, known-good ~830us): device-scope atomics ----
__global__ __launch_bounds__(256) void scatter_device(
    const float* __restrict__ beta, const float* __restrict__ tnet_weights,
    const long long* __restrict__ pin_pairs, const int* __restrict__ pin2node_map,
    float* __restrict__ out, int num_tnets)
{
    int t = blockIdx.x * blockDim.x + threadIdx.x;
    if (t >= num_tnets) return;
    long long pp = pin_pairs[t];
    float w = tnet_weights[t] * beta[0];
    atomicAdd(&out[pin2node_map[(int)(pp & 0xffffffffLL)]], w);
    atomicAdd(&out[pin2node_map[(int)(pp >> 32)]], w);
}

extern "C" void kernel_launch(void* const* d_in, const int* in_sizes, int n_in,
                              void* d_out, int out_size, void* d_ws, size_t ws_size,
                              hipStream_t stream) {
    const float* beta         = (const float*)d_in[0];
    const float* weights      = (const float*)d_in[1];
    const int*   flat_pins    = (const int*)d_in[2];
    const int*   pin2node     = (const int*)d_in[3];
    float* out = (float*)d_out;

    const int num_tnets = in_sizes[1];
    const int total     = in_sizes[2];       // 2 * num_tnets flat pin slots
    const int num_nodes = out_size;

    const size_t items1Bytes = (size_t)NB1 * 8 * CAP1R * sizeof(item_t);  // 141.6 MB
    const size_t items2Bytes = (size_t)NB2 * 8 * CAP2R * sizeof(item_t);  // 142.6 MB
    const size_t partBytes   = (size_t)NB2 * PARTS * ACC_NODES * sizeof(float); // 32 MB

    int* ctrl1 = (int*)d_ws;                           // 40*8 padded counters
    int* ctrl2 = (int*)((char*)d_ws + 32768);          // 64*8 padded counters
    const int gridTiles = (total + TILE - 1) / TILE;

    if (ws_size >= CTRL_BYTES + items1Bytes + items2Bytes + partBytes) {
        item_t* items1 = (item_t*)((char*)d_ws + CTRL_BYTES);
        item_t* items2 = (item_t*)((char*)d_ws + CTRL_BYTES + items1Bytes);
        float*  partials = (float*)((char*)d_ws + CTRL_BYTES + items1Bytes + items2Bytes);
        (void)hipMemsetAsync(d_ws, 0, CTRL_BYTES, stream);
        k1_partition_pins<<<gridTiles, THREADS, 0, stream>>>(
            flat_pins, weights, ctrl1, items1, total);
        k2_gather_partition<<<NB1 * 8 * TPB1R, THREADS, 0, stream>>>(
            items1, ctrl1, pin2node, ctrl2, items2);
        k3_accumulate_part<<<NB2 * PARTS, 1024, 0, stream>>>(
            items2, ctrl2, partials);
        const int i4slots = (num_nodes + 3) / 4;
        k4_reduce<<<(i4slots + 255) / 256, 256, 0, stream>>>(
            partials, beta, out, num_nodes);
    } else {
        (void)hipMemsetAsync(d_out, 0, (size_t)out_size * sizeof(float), stream);
        scatter_device<<<(num_tnets + 255) / 256, 256, 0, stream>>>(
            beta, weights, (const long long*)flat_pins, pin2node, out, num_tnets);
    }
}